// Round 1
// baseline (9166.824 us; speedup 1.0000x reference)
//
#include <hip/hip_runtime.h>
#include <math.h>

#define Bn    16
#define Tn    512
#define CENCn 128
#define EMBn  512
#define Hn    512
#define HHn   256
#define Pn    8
#define NTAGn 12
#define G4n   1024   // 4*HH

__device__ __forceinline__ float sigm(float x) { return 1.f / (1.f + expf(-x)); }

// ---------------------------------------------------------------------------
// C[M,N] = A[M,K] @ Bm[N,K]^T + b1[N] + b2[N]   (b1/b2 may be null)
// 128x128 tile, BK=16, 256 threads, 8x8 micro-tile, transposed LDS tiles.
// Requires M%128==0, N%128==0, K%16==0.
// ---------------------------------------------------------------------------
__global__ __launch_bounds__(256) void gemm_tn(
    const float* __restrict__ A, const float* __restrict__ Bm,
    float* __restrict__ C, const float* __restrict__ b1,
    const float* __restrict__ b2, int M, int N, int K)
{
    __shared__ float As[16][132];
    __shared__ float Bs[16][132];
    const int tid = threadIdx.x;
    const int tx = tid & 15, ty = tid >> 4;
    const int m0 = blockIdx.y * 128, n0 = blockIdx.x * 128;

    float acc[8][8];
#pragma unroll
    for (int i = 0; i < 8; i++)
#pragma unroll
        for (int j = 0; j < 8; j++) acc[i][j] = 0.f;

    const int r  = tid >> 2;        // 0..63
    const int cc = (tid & 3) * 4;   // 0,4,8,12

    for (int k0 = 0; k0 < K; k0 += 16) {
#pragma unroll
        for (int hh = 0; hh < 2; hh++) {
            const int row = r + hh * 64;
            const float4 va = *(const float4*)(A + (size_t)(m0 + row) * K + k0 + cc);
            As[cc + 0][row] = va.x; As[cc + 1][row] = va.y;
            As[cc + 2][row] = va.z; As[cc + 3][row] = va.w;
            const float4 vb = *(const float4*)(Bm + (size_t)(n0 + row) * K + k0 + cc);
            Bs[cc + 0][row] = vb.x; Bs[cc + 1][row] = vb.y;
            Bs[cc + 2][row] = vb.z; Bs[cc + 3][row] = vb.w;
        }
        __syncthreads();
#pragma unroll
        for (int kk = 0; kk < 16; kk++) {
            const float4 a0 = *(const float4*)&As[kk][ty * 4];
            const float4 a1 = *(const float4*)&As[kk][64 + ty * 4];
            const float4 b0 = *(const float4*)&Bs[kk][tx * 4];
            const float4 b1v = *(const float4*)&Bs[kk][64 + tx * 4];
            const float av[8] = {a0.x, a0.y, a0.z, a0.w, a1.x, a1.y, a1.z, a1.w};
            const float bv[8] = {b0.x, b0.y, b0.z, b0.w, b1v.x, b1v.y, b1v.z, b1v.w};
#pragma unroll
            for (int ii = 0; ii < 8; ii++)
#pragma unroll
                for (int jj = 0; jj < 8; jj++) acc[ii][jj] += av[ii] * bv[jj];
        }
        __syncthreads();
    }

    float bb[8];
#pragma unroll
    for (int jj = 0; jj < 8; jj++) {
        const int col = n0 + ((jj < 4) ? (tx * 4 + jj) : (64 + tx * 4 + jj - 4));
        bb[jj] = (b1 ? b1[col] : 0.f) + (b2 ? b2[col] : 0.f);
    }
#pragma unroll
    for (int ii = 0; ii < 8; ii++) {
        const int row = m0 + ((ii < 4) ? (ty * 4 + ii) : (64 + ty * 4 + ii - 4));
        float4 v0, v1;
        v0.x = acc[ii][0] + bb[0]; v0.y = acc[ii][1] + bb[1];
        v0.z = acc[ii][2] + bb[2]; v0.w = acc[ii][3] + bb[3];
        v1.x = acc[ii][4] + bb[4]; v1.y = acc[ii][5] + bb[5];
        v1.z = acc[ii][6] + bb[6]; v1.w = acc[ii][7] + bb[7];
        *(float4*)(C + (size_t)row * N + n0 + tx * 4) = v0;
        *(float4*)(C + (size_t)row * N + n0 + 64 + tx * 4) = v1;
    }
}

// ---------------------------------------------------------------------------
// One encoder time step, both directions. grid = 64 blocks (dir*32 + group),
// 256 threads. Each block owns 8 h-dims (32 Whh rows: {j, 256+j, 512+j, 768+j}),
// computes gates for all 16 batches, applies masked LSTM cell, writes concat
// output buffer (fwd -> cols [0,256), rev -> cols [256,512) at reversed t).
// ---------------------------------------------------------------------------
__global__ __launch_bounds__(256) void enc_step(
    const float* __restrict__ Gf, const float* __restrict__ Gr,
    const float* __restrict__ WhhF, const float* __restrict__ WhhR,
    float* __restrict__ h_ws, float* __restrict__ c_ws,
    float* __restrict__ outbuf, const int* __restrict__ lens, int t)
{
    __shared__ float wsh[32][257];
    __shared__ float hsh[16][256];
    __shared__ float gsh[512];
    const int tid = threadIdx.x;
    const int dir = blockIdx.x >> 5;
    const int g   = blockIdx.x & 31;
    const float* Whh = dir ? WhhR : WhhF;
    const float* Gx  = dir ? Gr : Gf;

    // stage Whh rows for this group's 8 h-dims (rows hd + 256*q), coalesced
#pragma unroll
    for (int i = 0; i < 8; i++) {
        const int f4 = i * 256 + tid;          // 0..2047 (float4 units)
        const int r32 = f4 >> 6;               // 0..31  (= q*8 + hdl)
        const int kc = (f4 & 63) * 4;
        const int q = r32 >> 3, hdl = r32 & 7;
        const float4 v = *(const float4*)(Whh + (size_t)(g * 8 + hdl + (q << 8)) * HHn + kc);
        wsh[r32][kc + 0] = v.x; wsh[r32][kc + 1] = v.y;
        wsh[r32][kc + 2] = v.z; wsh[r32][kc + 3] = v.w;
    }
    // stage full h for this direction
#pragma unroll
    for (int i = 0; i < 4; i++) {
        const int f4 = i * 256 + tid;          // 0..1023
        const int b = f4 >> 6;
        const int kc = (f4 & 63) * 4;
        *(float4*)&hsh[b][kc] = *(const float4*)(h_ws + ((dir * 16 + b) << 8) + kc);
    }
    __syncthreads();

    const int b0 = tid >> 5, r0 = tid & 31;    // output (b0,r0) and (b0+8,r0)
    float acc0 = 0.f, acc1 = 0.f;
#pragma unroll 8
    for (int k = 0; k < 256; k++) {
        const float wv = wsh[r0][k];
        acc0 += hsh[b0][k] * wv;
        acc1 += hsh[b0 + 8][k] * wv;
    }
    {
        const int q = r0 >> 3, hdl = r0 & 7;
        const int j = g * 8 + hdl + (q << 8);
        const int lb0 = lens[b0], lb1 = lens[b0 + 8];
        const int idx0 = dir ? max(lb0 - 1 - t, 0) : t;
        const int idx1 = dir ? max(lb1 - 1 - t, 0) : t;
        gsh[(b0 << 5) + r0]       = acc0 + Gx[(size_t)(idx0 * Bn + b0) * G4n + j];
        gsh[((b0 + 8) << 5) + r0] = acc1 + Gx[(size_t)(idx1 * Bn + b0 + 8) * G4n + j];
    }
    __syncthreads();

    if (tid < 128) {
        const int b = tid >> 3, hdl = tid & 7;
        const int lb = lens[b];
        if (t < lb) {                           // masked: state frozen / out zero otherwise
            const int hd = g * 8 + hdl;
            const float gi = gsh[(b << 5) + hdl];
            const float gf = gsh[(b << 5) + 8 + hdl];
            const float gg = gsh[(b << 5) + 16 + hdl];
            const float go = gsh[(b << 5) + 24 + hdl];
            const int sidx = ((dir * 16 + b) << 8) + hd;
            const float c_new = sigm(gf) * c_ws[sidx] + sigm(gi) * tanhf(gg);
            const float h_new = sigm(go) * tanhf(c_new);
            h_ws[sidx] = h_new;
            c_ws[sidx] = c_new;
            const int trow = dir ? (lb - 1 - t) : t;
            outbuf[(size_t)(trow * Bn + b) * Hn + dir * HHn + hd] = h_new;
        }
    }
}

// ---------------------------------------------------------------------------
// Segment-scan cell + fused final FC. grid = B*T blocks (stream-major b*T+t0),
// 256 threads (one per h-dim). GT = h@Whh^T (no bias), Gx = u@Wih^T + biases.
// Adds this step's FC contribution (fwd cols [0,256) / rev cols [256,512) of
// Wfc) into out, which was pre-initialized to bfc.
// ---------------------------------------------------------------------------
__global__ __launch_bounds__(256) void seg_cell(
    const float* __restrict__ GT, const float* __restrict__ Gx,
    float* __restrict__ Hs, float* __restrict__ Cs,
    const float* __restrict__ Wfc, float* __restrict__ outp,
    const int* __restrict__ lens, int k, int dir)
{
    __shared__ float hshs[256];
    const int s = blockIdx.x;
    const int b = s >> 9, t0 = s & 511;
    const int tid = threadIdx.x;
    const int tau = dir ? (t0 - k) : (t0 + k);
    const int tauc = min(max(tau, 0), Tn - 1);    // clamped; only affects never-consumed outputs
    const size_t grow = ((size_t)(b << 9) + tauc) * G4n;
    const size_t srow = (size_t)s * G4n;

    const float gi = GT[srow + tid]       + Gx[grow + tid];
    const float gf = GT[srow + 256 + tid] + Gx[grow + 256 + tid];
    const float gg = GT[srow + 512 + tid] + Gx[grow + 512 + tid];
    const float go = GT[srow + 768 + tid] + Gx[grow + 768 + tid];
    const size_t hidx = (size_t)s * 256 + tid;
    const float c_new = sigm(gf) * Cs[hidx] + sigm(gi) * tanhf(gg);
    const float h_new = sigm(go) * tanhf(c_new);
    Cs[hidx] = c_new;
    Hs[hidx] = h_new;
    hshs[tid] = h_new;
    __syncthreads();

    const int t_out = dir ? t0 : (t0 + k);
    const bool valid = dir ? (t0 >= k && t0 < lens[b])
                           : (t_out < Tn && t_out < lens[b]);
    if (valid && tid < 192) {
        const int n = tid >> 4, l = tid & 15;
        const int off = dir ? 256 : 0;
        float a = 0.f;
#pragma unroll
        for (int e = 0; e < 16; e++)
            a += hshs[l + (e << 4)] * Wfc[n * Hn + off + l + (e << 4)];
        a += __shfl_down(a, 8, 16);
        a += __shfl_down(a, 4, 16);
        a += __shfl_down(a, 2, 16);
        a += __shfl_down(a, 1, 16);
        if (l == 0) {
            const size_t oidx = (((size_t)(b << 9) + t_out) * Pn + k) * NTAGn + n;
            outp[oidx] += a;
        }
    }
}

// u[b*T+t, :] = in[t*B+b, :]
__global__ __launch_bounds__(256) void transpose_tb(
    const float* __restrict__ in, float* __restrict__ outp)
{
    const int s = blockIdx.x;
    const int b = s >> 9, t = s & 511;
    const int tid = threadIdx.x;
    const float* src = in + (size_t)(t * Bn + b) * Hn;
    float* dst = outp + (size_t)s * Hn;
    dst[tid] = src[tid];
    dst[tid + 256] = src[tid + 256];
}

__global__ __launch_bounds__(256) void init_out(
    float* __restrict__ outp, const float* __restrict__ bfc, int n)
{
    const int i = blockIdx.x * 256 + threadIdx.x;
    if (i < n) outp[i] = bfc[i % NTAGn];
}

// ---------------------------------------------------------------------------
extern "C" void kernel_launch(void* const* d_in, const int* in_sizes, int n_in,
                              void* d_out, int out_size, void* d_ws, size_t ws_size,
                              hipStream_t stream)
{
    (void)in_sizes; (void)n_in; (void)out_size; (void)ws_size;
    const float* x      = (const float*)d_in[0];
    const float* h0     = (const float*)d_in[1];
    const float* c0     = (const float*)d_in[2];
    const float* W_emb  = (const float*)d_in[3];
    const float* b_emb  = (const float*)d_in[4];
    const float* Wih    = (const float*)d_in[5];
    const float* Whh    = (const float*)d_in[6];
    const float* bih    = (const float*)d_in[7];
    const float* bhh    = (const float*)d_in[8];
    const float* Wih_sf = (const float*)d_in[9];
    const float* Whh_sf = (const float*)d_in[10];
    const float* bih_sf = (const float*)d_in[11];
    const float* bhh_sf = (const float*)d_in[12];
    const float* Wih_sr = (const float*)d_in[13];
    const float* Whh_sr = (const float*)d_in[14];
    const float* bih_sr = (const float*)d_in[15];
    const float* bhh_sr = (const float*)d_in[16];
    const float* Wfc    = (const float*)d_in[17];
    const float* bfc    = (const float*)d_in[18];
    const int*   lens   = (const int*)d_in[19];
    float* out = (float*)d_out;
    float* w   = (float*)d_ws;

    // workspace layout (floats); GT aliases bufA+bufB (both dead by then)
    float* bufA = w;                  // 4194304  [T*B,512]
    float* bufB = w + 4194304;        // 4194304
    float* G0   = w + 8388608;        // 8388608  [8192,1024]
    float* G1   = w + 16777216;       // 8388608
    float* U    = w + 25165824;       // 4194304  [B*T,512]
    float* Hs   = w + 29360128;       // 2097152  [8192,256]
    float* Cs   = w + 31457280;       // 2097152
    float* h_ws = w + 33554432;       // 8192 [2][16][256]
    float* c_ws = w + 33562624;       // 8192
    float* GT   = w;                  // 8388608 (alias)

    const dim3 blk(256);

    // 1. embedding: bufA = x @ W_emb^T + b_emb
    gemm_tn<<<dim3(EMBn / 128, (Tn * Bn) / 128), blk, 0, stream>>>(
        x, W_emb, bufA, b_emb, nullptr, Tn * Bn, EMBn, CENCn);

    // 2. encoder: 2 bidirectional layers
    for (int l = 0; l < 2; l++) {
        const float* Xin = l ? bufB : bufA;
        float* O = l ? bufA : bufB;
        const float* WihF = Wih + (size_t)(2 * l) * G4n * Hn;
        const float* WihR = Wih + (size_t)(2 * l + 1) * G4n * Hn;
        const float* WhhF = Whh + (size_t)(2 * l) * G4n * HHn;
        const float* WhhR = Whh + (size_t)(2 * l + 1) * G4n * HHn;
        gemm_tn<<<dim3(G4n / 128, 64), blk, 0, stream>>>(
            Xin, WihF, G0, bih + (size_t)(2 * l) * G4n, bhh + (size_t)(2 * l) * G4n,
            Tn * Bn, G4n, Hn);
        gemm_tn<<<dim3(G4n / 128, 64), blk, 0, stream>>>(
            Xin, WihR, G1, bih + (size_t)(2 * l + 1) * G4n, bhh + (size_t)(2 * l + 1) * G4n,
            Tn * Bn, G4n, Hn);
        hipMemsetAsync(O, 0, (size_t)4194304 * 4, stream);
        hipMemcpyAsync(h_ws, h0 + (size_t)(2 * l) * Bn * HHn, (size_t)2 * Bn * HHn * 4,
                       hipMemcpyDeviceToDevice, stream);
        hipMemcpyAsync(c_ws, c0 + (size_t)(2 * l) * Bn * HHn, (size_t)2 * Bn * HHn * 4,
                       hipMemcpyDeviceToDevice, stream);
        for (int t = 0; t < Tn; t++)
            enc_step<<<64, blk, 0, stream>>>(G0, G1, WhhF, WhhR, h_ws, c_ws, O, lens, t);
    }

    // 3. u = transpose(bufA): [T,B,H] -> [B,T,H]
    transpose_tb<<<Bn * Tn, blk, 0, stream>>>(bufA, U);

    // 4. segment-scan input transforms
    gemm_tn<<<dim3(G4n / 128, 64), blk, 0, stream>>>(
        U, Wih_sf, G0, bih_sf, bhh_sf, Bn * Tn, G4n, Hn);
    gemm_tn<<<dim3(G4n / 128, 64), blk, 0, stream>>>(
        U, Wih_sr, G1, bih_sr, bhh_sr, Bn * Tn, G4n, Hn);

    // 5. output = bias (covers all invalid/masked slots)
    init_out<<<(Bn * Tn * Pn * NTAGn + 255) / 256, blk, 0, stream>>>(
        out, bfc, Bn * Tn * Pn * NTAGn);

    // 6. segment scans, fwd then rev, FC fused into cell kernel
    for (int dir = 0; dir < 2; dir++) {
        const float* Whh_s = dir ? Whh_sr : Whh_sf;
        const float* Gx = dir ? G1 : G0;
        hipMemsetAsync(Hs, 0, (size_t)2097152 * 4, stream);
        hipMemsetAsync(Cs, 0, (size_t)2097152 * 4, stream);
        for (int k = 0; k < Pn; k++) {
            if (k == 0)
                hipMemsetAsync(GT, 0, (size_t)8388608 * 4, stream);
            else
                gemm_tn<<<dim3(G4n / 128, 64), blk, 0, stream>>>(
                    Hs, Whh_s, GT, nullptr, nullptr, Bn * Tn, G4n, HHn);
            seg_cell<<<Bn * Tn, blk, 0, stream>>>(GT, Gx, Hs, Cs, Wfc, out, lens, k, dir);
        }
    }
}